// Round 9
// baseline (306.351 us; speedup 1.0000x reference)
//
#include <hip/hip_runtime.h>
#include <stdint.h>

typedef __bf16 bf16;
typedef __bf16 bf16x4 __attribute__((ext_vector_type(4)));
typedef __bf16 bf16x8 __attribute__((ext_vector_type(8)));
typedef float f32x4 __attribute__((ext_vector_type(4)));
typedef short short4v __attribute__((ext_vector_type(4)));

#define NB 4
#define NS 2048
#define ND 1024
#define NH 16
#define NHD 64
#define QSCALE 0.1803368801111204f   // 0.125 * log2(e): scores in log2 domain
#define FMAX   8.0f                  // fixed softmax shift (log2 domain)
#define CPITCH 136                   // epilogue LDS pitch: 272B rows, 16B aligned

typedef const __attribute__((address_space(1))) unsigned GU;
typedef __attribute__((address_space(3))) unsigned LU;

__device__ __forceinline__ bf16x8 load8f(const float* p) {
    float4 a = *(const float4*)p;
    float4 b = *(const float4*)(p + 4);
    bf16x8 r;
    r[0] = (bf16)a.x; r[1] = (bf16)a.y; r[2] = (bf16)a.z; r[3] = (bf16)a.w;
    r[4] = (bf16)b.x; r[5] = (bf16)b.y; r[6] = (bf16)b.z; r[7] = (bf16)b.w;
    return r;
}
__device__ __forceinline__ void store8(bf16* p, bf16x8 v) { *(bf16x8*)p = v; }
__device__ __forceinline__ void store8(float* p, bf16x8 v) {
    float4 a; a.x = (float)v[0]; a.y = (float)v[1]; a.z = (float)v[2]; a.w = (float)v[3];
    float4 b; b.x = (float)v[4]; b.y = (float)v[5]; b.z = (float)v[6]; b.w = (float)v[7];
    *(float4*)p = a; *(float4*)(p + 4) = b;
}

// 16x16x16 bf16 MFMA (K=16): A/B frags are 4 bf16/lane, k = quad*4+j.
// Builtin checks nested under __HIP_DEVICE_COMPILE__ (host pass parses too).
__device__ __forceinline__ f32x4 mfma16(bf16x4 a, bf16x4 b, f32x4 c) {
#ifdef __HIP_DEVICE_COMPILE__
#if __has_builtin(__builtin_amdgcn_mfma_f32_16x16x16bf16_1k)
    return __builtin_amdgcn_mfma_f32_16x16x16bf16_1k(
        __builtin_bit_cast(short4v, a), __builtin_bit_cast(short4v, b), c, 0, 0, 0);
#else
    f32x4 d;
    asm("v_mfma_f32_16x16x16_bf16 %0, %1, %2, %3"
        : "=v"(d) : "v"(a), "v"(b), "v"(c));
    return d;
#endif
#else
    return c;  // host stub, never executed
#endif
}

// attn LDS swizzle: XOR col by quad-of-row*16; preserves >=4-elem contiguity.
__device__ __forceinline__ int sw(int row, int col) {
    return row * 72 + (col ^ (((row >> 2) & 3) * 16));
}

// One-shot fp32 -> bf16 conversion of x, Wqkv, Wproj (biases stay fp32).
__global__ __launch_bounds__(256)
void convert_kernel(const float* __restrict__ s0, bf16* __restrict__ d0, int n0,
                    const float* __restrict__ s1, bf16* __restrict__ d1, int n1,
                    const float* __restrict__ s2, bf16* __restrict__ d2, int n2)
{
    int idx = (blockIdx.x * 256 + threadIdx.x) * 8;
    const float* s; bf16* d;
    if (idx < n0)              { s = s0 + idx;  d = d0 + idx; }
    else if ((idx -= n0) < n1) { s = s1 + idx;  d = d1 + idx; }
    else if ((idx -= n1) < n2) { s = s2 + idx;  d = d2 + idx; }
    else return;
    *(bf16x8*)d = load8f(s);
}

// LDS-staged coalesced epilogue. Requires prior __syncthreads() (K-loop tail).
// MODE 0 class by n0: 0=Q (scaled, [B,H,S,HD] via O1), 1=K (O2),
//                     2=V (transposed [B,H,HD,S] via O0). MODE 1: O0[M,N].
template<typename TO, int MODE>
__device__ __forceinline__ void gemm_epilogue(
    f32x4 (&acc)[4][4], bf16* Ls, const float* __restrict__ bias,
    TO* __restrict__ O0, bf16* __restrict__ O1, bf16* __restrict__ O2,
    int N, int m0, int n0, int tid)
{
    const int lane = tid & 63;
    const int w = tid >> 6, wm = w >> 1, wn = w & 1;
    const int lr = lane & 15, quad = lane >> 4;
    const int cls = (MODE == 0) ? (n0 >> 10) : 1;

    if (MODE == 0 && cls == 2) {
        // V: stage transposed Cv[col][row], then coalesced stores along S
#pragma unroll
        for (int im = 0; im < 4; ++im) {
            int rowb = wm * 64 + im * 16 + quad * 4;
#pragma unroll
            for (int in = 0; in < 4; ++in) {
                int col = wn * 64 + in * 16 + lr;
                float bv = bias[n0 + col];
                bf16x4 pv;
#pragma unroll
                for (int r = 0; r < 4; ++r) pv[r] = (bf16)(acc[im][in][r] + bv);
                *(bf16x4*)&Ls[col * CPITCH + rowb] = pv;
            }
        }
        __syncthreads();
        const int b = m0 >> 11, s0 = m0 & 2047;
#pragma unroll
        for (int p = 0; p < 8; ++p) {
            int idx = tid + 256 * p;
            int col = idx & 127, mg = idx >> 7;
            bf16x8 v8 = *(const bf16x8*)&Ls[col * CPITCH + mg * 8];
            int ncol = n0 + col;
            int h = (ncol >> 6) & 15, hd = ncol & 63;
            *(bf16x8*)&((bf16*)O0)[((size_t)(b * NH + h) * NHD + hd) * NS + s0 + mg * 8] = v8;
        }
    } else {
#pragma unroll
        for (int im = 0; im < 4; ++im) {
            int rowb = wm * 64 + im * 16 + quad * 4;
#pragma unroll
            for (int in = 0; in < 4; ++in) {
                int col = wn * 64 + in * 16 + lr;
                float bv = bias[n0 + col];
#pragma unroll
                for (int r = 0; r < 4; ++r) {
                    float v = acc[im][in][r] + bv;
                    if (MODE == 0 && cls == 0) v *= QSCALE;
                    Ls[(rowb + r) * CPITCH + col] = (bf16)v;
                }
            }
        }
        __syncthreads();
#pragma unroll
        for (int p = 0; p < 8; ++p) {
            int idx = tid + 256 * p;
            int row = idx >> 4, colg = (idx & 15) * 8;
            bf16x8 v8 = *(const bf16x8*)&Ls[row * CPITCH + colg];
            if (MODE == 0) {
                int ncol = n0 + colg;
                int h = (ncol >> 6) & 15, hd = ncol & 63;
                int m = m0 + row, b = m >> 11, s = m & 2047;
                bf16* dst = (cls == 0) ? O1 : O2;
                *(bf16x8*)&dst[((size_t)(b * NH + h) * NS + s) * NHD + hd] = v8;
            } else {
                store8(&O0[(size_t)(m0 + row) * N + n0 + colg], v8);
            }
        }
    }
}

// bf16 GEMM: C[M,N] = X[M,K] @ W[N,K]^T + bias; global_load_lds staging.
template<typename TO, int MODE>
__global__ __launch_bounds__(256, 3)
void gemm_bt(const bf16* __restrict__ Xp, const bf16* __restrict__ Wp,
             const float* __restrict__ bias, TO* __restrict__ O0,
             bf16* __restrict__ O1, bf16* __restrict__ O2, int N, int K)
{
    __shared__ union {
        struct { bf16 Ah[128 * 32]; bf16 Bh[128 * 32]; } s;
        bf16 C[128 * CPITCH];
    } u;
    const int tid  = threadIdx.x;
    const int lane = tid & 63;
    const int w    = tid >> 6;
    const int wm   = w >> 1, wn = w & 1;
    const int lr   = lane & 15, quad = lane >> 4;
    const int m0   = blockIdx.y * 128;
    const int n0   = blockIdx.x * 128;

    const int srow = w * 32 + (lane >> 2);
    const int scol = (lane & 3) * 8;
    const bf16* gA = Xp + (size_t)(m0 + srow) * K + scol;
    const bf16* gB = Wp + (size_t)(n0 + srow) * K + scol;

    f32x4 acc[4][4] = {};

    for (int k0 = 0; k0 < K; k0 += 32) {
#pragma unroll
        for (int c = 0; c < 2; ++c) {
            __builtin_amdgcn_global_load_lds((GU*)(gA + (size_t)c * 16 * K + k0),
                                             (LU*)&u.s.Ah[(w * 32 + c * 16) * 32], 16, 0, 0);
            __builtin_amdgcn_global_load_lds((GU*)(gB + (size_t)c * 16 * K + k0),
                                             (LU*)&u.s.Bh[(w * 32 + c * 16) * 32], 16, 0, 0);
        }
        __syncthreads();

        bf16x8 af[4], bfr[4];
#pragma unroll
        for (int im = 0; im < 4; ++im)
            af[im] = *(const bf16x8*)(&u.s.Ah[(wm * 64 + im * 16 + lr) * 32 + quad * 8]);
#pragma unroll
        for (int in = 0; in < 4; ++in)
            bfr[in] = *(const bf16x8*)(&u.s.Bh[(wn * 64 + in * 16 + lr) * 32 + quad * 8]);
#pragma unroll
        for (int im = 0; im < 4; ++im)
#pragma unroll
            for (int in = 0; in < 4; ++in)
                acc[im][in] = __builtin_amdgcn_mfma_f32_16x16x32_bf16(
                    af[im], bfr[in], acc[im][in], 0, 0, 0);
        __syncthreads();
    }

    gemm_epilogue<TO, MODE>(acc, u.C, bias, O0, O1, O2, N, m0, n0, tid);
}

// Flash attention, causal, fixed-shift log2 softmax, P in registers.
// 128-row Q tiles; each wave owns TWO 16-row Q subtiles (sub*64 + w*16).
// K/V fragment LDS reads are shared across both subtiles; barriers per
// unit of work halved vs 64-row tiles.
__global__ __launch_bounds__(256, 4)
void attn_kernel(const bf16* __restrict__ Q, const bf16* __restrict__ K,
                 const bf16* __restrict__ Vt_g, bf16* __restrict__ ctx)
{
    const int jtp = 15 - (int)(blockIdx.x >> 6);   // 128-row Q-tile, heavy first
    const int bh = blockIdx.x & 63;
    const int b  = bh >> 4, h = bh & 15;
    const int q0 = jtp * 128;
    const bf16* Qp = Q + (size_t)bh * NS * NHD;
    const bf16* Kp = K + (size_t)bh * NS * NHD;
    const bf16* Vp = Vt_g + (size_t)bh * NHD * NS;   // [hd][S]

    __shared__ bf16 Qh[128 * 72];
    __shared__ bf16 Kh[64 * 72];
    __shared__ bf16 Vh[64 * 72];   // V^T[hd][k]

    const int tid  = threadIdx.x;
    const int lane = tid & 63;
    const int w    = tid >> 6;
    const int lr   = lane & 15, quad = lane >> 4;

    // stage Q (128x64): 1024 x 16B
#pragma unroll
    for (int i = 0; i < 4; ++i) {
        int c = tid + 256 * i;
        int row = c >> 3, ch = c & 7;
        *(bf16x8*)(&Qh[sw(row, ch * 8)]) =
            *(const bf16x8*)(Qp + (size_t)(q0 + row) * NHD + ch * 8);
    }

    const int qrow0 = q0 + w * 16 + lr;        // subtile 0 Q row
    const int qrow1 = qrow0 + 64;              // subtile 1 Q row
    float l0 = 0.f, l1 = 0.f;
    f32x4 acco0[4] = {}, acco1[4] = {};        // O^T per subtile

    const int nkt = 2 * jtp + 2;
    for (int kt = 0; kt < nkt; ++kt) {
        __syncthreads();
#pragma unroll
        for (int i = 0; i < 2; ++i) {
            int c = tid + 256 * i;
            int row = c >> 3, ch = c & 7;
            *(bf16x8*)(&Kh[sw(row, ch * 8)]) =
                *(const bf16x8*)(Kp + (size_t)(kt * 64 + row) * NHD + ch * 8);
            *(bf16x8*)(&Vh[sw(row, ch * 8)]) =
                *(const bf16x8*)(Vp + (size_t)row * NS + kt * 64 + ch * 8);
        }
        __syncthreads();

        const bool act0 = (kt <= 2 * jtp);     // sub0 fully masked on last tile

        // S^T = K @ Q^T for both subtiles; K-frag shared
        f32x4 sacc0[4] = {}, sacc1[4] = {};
#pragma unroll
        for (int ks = 0; ks < 2; ++ks) {
            bf16x8 bq0 = *(const bf16x8*)(&Qh[sw(w * 16 + lr, ks * 32 + quad * 8)]);
            bf16x8 bq1 = *(const bf16x8*)(&Qh[sw(64 + w * 16 + lr, ks * 32 + quad * 8)]);
#pragma unroll
            for (int kn = 0; kn < 4; ++kn) {
                bf16x8 ak = *(const bf16x8*)(&Kh[sw(kn * 16 + lr, ks * 32 + quad * 8)]);
                if (act0)
                    sacc0[kn] = __builtin_amdgcn_mfma_f32_16x16x32_bf16(ak, bq0, sacc0[kn], 0, 0, 0);
                sacc1[kn] = __builtin_amdgcn_mfma_f32_16x16x32_bf16(ak, bq1, sacc1[kn], 0, 0, 0);
            }
        }

        // softmax in registers; p-values land directly in x16 B-frag layout
        const bool diag0 = (kt == 2 * jtp);
        const bool diag1 = (kt == 2 * jtp + 1);
        bf16x4 pf0[4], pf1[4];
#pragma unroll
        for (int kn = 0; kn < 4; ++kn) {
#pragma unroll
            for (int r = 0; r < 4; ++r) {
                int kcol = kt * 64 + kn * 16 + quad * 4 + r;
                if (act0) {
                    float x = sacc0[kn][r];
                    if (diag0) x = (kcol <= qrow0) ? x : -INFINITY;
                    float p = __builtin_amdgcn_exp2f(x - FMAX);
                    l0 += p;
                    pf0[kn][r] = (bf16)p;
                }
                float y = sacc1[kn][r];
                if (diag1) y = (kcol <= qrow1) ? y : -INFINITY;
                float p1 = __builtin_amdgcn_exp2f(y - FMAX);
                l1 += p1;
                pf1[kn][r] = (bf16)p1;
            }
        }

        // O^T += V^T @ P^T  (16x16x16); V-frag shared across subtiles
#pragma unroll
        for (int kn = 0; kn < 4; ++kn) {
#pragma unroll
            for (int jn = 0; jn < 4; ++jn) {
                bf16x4 av = *(const bf16x4*)(&Vh[sw(jn * 16 + lr, kn * 16 + quad * 4)]);
                if (act0) acco0[jn] = mfma16(av, pf0[kn], acco0[jn]);
                acco1[jn] = mfma16(av, pf1[kn], acco1[jn]);
            }
        }
    }

    // per-lane l: reduce across the 4 quads
    l0 += __shfl_xor(l0, 16); l0 += __shfl_xor(l0, 32);
    l1 += __shfl_xor(l1, 16); l1 += __shfl_xor(l1, 32);
    float rinv0 = 1.0f / l0, rinv1 = 1.0f / l1;

    // epilogue: O^T -> Qh (dead) packed b64 rows, then coalesced b128 out
    __syncthreads();
#pragma unroll
    for (int jn = 0; jn < 4; ++jn) {
        bf16x4 p0, p1;
#pragma unroll
        for (int r = 0; r < 4; ++r) {
            p0[r] = (bf16)(acco0[jn][r] * rinv0);
            p1[r] = (bf16)(acco1[jn][r] * rinv1);
        }
        *(bf16x4*)&Qh[(w * 16 + lr) * 72 + jn * 16 + quad * 4] = p0;
        *(bf16x4*)&Qh[(64 + w * 16 + lr) * 72 + jn * 16 + quad * 4] = p1;
    }
    __syncthreads();
#pragma unroll
    for (int p = 0; p < 4; ++p) {
        int idx = tid + 256 * p;
        int row = idx >> 3, colg = (idx & 7) * 8;
        bf16x8 v8 = *(const bf16x8*)&Qh[row * 72 + colg];
        *(bf16x8*)&ctx[((size_t)(b * NS) + q0 + row) * ND + h * NHD + colg] = v8;
    }
}

extern "C" void kernel_launch(void* const* d_in, const int* in_sizes, int n_in,
                              void* d_out, int out_size, void* d_ws, size_t ws_size,
                              hipStream_t stream) {
    const float* x     = (const float*)d_in[0];
    const float* Wqkv  = (const float*)d_in[1];
    const float* bqkv  = (const float*)d_in[2];
    const float* Wproj = (const float*)d_in[3];
    const float* bproj = (const float*)d_in[4];
    float* out = (float*)d_out;

    const size_t per = (size_t)NB * NH * NS * NHD;  // 8,388,608 elems
    bf16* q_ws = (bf16*)d_ws;
    bf16* k_ws = q_ws + per;
    bf16* v_ws = k_ws + per;        // V transposed [B,H,HD,S]
    bf16* x_bf = v_ws + per;        // x as bf16; reused as ctx after QKV GEMM
    bf16* c_ws = x_bf;              // alias: x_bf dead once QKV GEMM completes
    bf16* wq_bf = x_bf + per;       // Wqkv bf16
    bf16* wp_bf = wq_bf + (size_t)3 * ND * ND;  // Wproj bf16

    const int n0 = NB * NS * ND;        // 8,388,608
    const int n1 = 3 * ND * ND;         // 3,145,728
    const int n2 = ND * ND;             // 1,048,576
    convert_kernel<<<(n0 + n1 + n2) / (256 * 8), 256, 0, stream>>>(
        x, x_bf, n0, Wqkv, wq_bf, n1, Wproj, wp_bf, n2);

    dim3 gq(3 * ND / 128, NB * NS / 128);
    gemm_bt<bf16, 0><<<gq, 256, 0, stream>>>(
        x_bf, wq_bf, bqkv, v_ws, q_ws, k_ws, 3 * ND, ND);

    attn_kernel<<<dim3(NB * NH * 16), 256, 0, stream>>>(q_ws, k_ws, v_ws, c_ws);

    dim3 gp(ND / 128, NB * NS / 128);
    gemm_bt<float, 1><<<gp, 256, 0, stream>>>(
        c_ws, wp_bf, bproj, out, nullptr, nullptr, ND, ND);
}